// Round 15
// baseline (79.727 us; speedup 1.0000x reference)
//
#include <hip/hip_runtime.h>
#include <hip/hip_bf16.h>

// ws layout (requires ws_size >= 221184 B):
//   [0, 221184) : weights as bf16 in 16x16x32 MFMA B-fragment order
#define WS_W_OFF    0

typedef __attribute__((ext_vector_type(8))) short s16x8;
typedef __attribute__((ext_vector_type(4))) float f32x4;

#define GLOBAL_AS __attribute__((address_space(1)))
#define LDS_AS    __attribute__((address_space(3)))

__device__ __forceinline__ unsigned short f2bf(float f) {
  unsigned u = __builtin_bit_cast(unsigned, f);
  u = u + 0x7fffu + ((u >> 16) & 1u);
  return (unsigned short)(u >> 16);
}

// ---------------------------------------------------------------------------
// Weight prep (mapping VERIFIED rounds 5/9/10/12/13): W[cout][cin][tap] fp32
// -> bf16 16x16x32 B-fragments. Fragment f = (tap*2+h)*4+nf holds B[n][k]
// for n = nf*16 + (lane&15), cin = h*32 + (lane>>4)*8 + j.
// bf16 index = (f*64 + lane)*8 + j; 4 KB tile per (tap,h) at (tap*2+h)*4096.
__global__ void wprep_kernel(const float* __restrict__ w,
                             unsigned short* __restrict__ wsw) {
  int t = blockIdx.x * 256 + threadIdx.x;        // 110592 threads exactly
  int tap  = t % 27;
  int cin  = (t / 27) & 63;
  int cout = t / (27 * 64);
  int h   = cin >> 5;
  int q   = (cin >> 3) & 3;
  int j   = cin & 7;
  int nf  = cout >> 4;
  int lane = q * 16 + (cout & 15);
  int dst = (((tap * 2 + h) * 4 + nf) * 64 + lane) * 8 + j;
  wsw[dst] = f2bf(w[t]);
}

// ---------------------------------------------------------------------------
// Implicit-GEMM conv, ALL-LDS operand feed, with FUSED x staging:
// the halo is gathered directly from NCDHW fp32 x (8 cin per thread, each
// load lane-coalesced along gx), converted to bf16 in-register, and written
// via one ds_write_b128 per task into the VERIFIED linear halo layout
// (pos p at halo[p*64], 16B cin-chunk c at +c*16; A-read = 8 dwords/bank =
// ds_read_b128 floor). This deletes the 48 MB x-transpose prep round-trip.
//
// Block = (b, z-quad, y-quad): 4z x 4y x 32x = 512 outputs x 64 couts,
// 512 threads = 8 waves, grid 256 = exactly 1 block/CU, ONE generation.
// Wave w: zo = w>>1 (z-row), yo2 = (w&1)*2 (y-pair): M_w = 64, N_w = 64.
// K = 64 as two cin-halves; per half: 3 kd-groups of 9 taps, B double-
// buffered in LDS via global_load_lds (staged a full group ahead; the
// barrier's vmcnt drain is covered by the 9-tap compute window).
// Compute core / barrier schedule / epilogue byte-identical to round 12.
__global__ __launch_bounds__(512, 1) void conv_kernel(const float* __restrict__ x,
                                                      const float* __restrict__ bias,
                                                      float* __restrict__ out,
                                                      const char* __restrict__ ws) {
  __shared__ __align__(16) unsigned char halo[1224 * 64];   // 78336 B
  __shared__ __align__(16) unsigned char blds[2][36864];    // 73728 B

  const int tid  = threadIdx.x;
  const int lane = tid & 63;
  const int w    = tid >> 6;                     // wave 0..7
  const int zo   = w >> 1;                       // z-row in quad
  const int yo2  = (w & 1) * 2;                  // y-pair base
  // XCD swizzle (256 % 8 == 0 -> bijective): 32 contiguous logical blocks
  // per XCD (fixed b, 4 consecutive z-quads) -> x slab L2-resident.
  const int logical = (blockIdx.x & 7) * 32 + (blockIdx.x >> 3);
  const int yq = logical & 7, zq = (logical >> 3) & 7, b = logical >> 6;
  const int z0 = zq * 4, y0 = yq * 4;

  const int r15 = lane & 15;
  const int hi4 = lane >> 4;

  // ---- fused halo staging: 4896 tasks (1224 pos x 4 cin-chunks) per half.
  // Task: gather 8 cin of one position from NCDHW fp32 x (loads coalesced
  // along gx across lanes), cvt->bf16, one ds_write_b128. OOB -> 0.
  auto stage_halo = [&](int h) {
    #pragma unroll 1
    for (int r = 0; r < 10; ++r) {
      int task = r * 512 + tid;
      if (task < 4896) {
        int pos = task >> 2, ch = task & 3;
        int hz = pos / 204; int rem = pos - hz * 204;      // 204 = 6*34
        int hy = rem / 34;  int hx = rem - hy * 34;
        int gz = z0 + hz - 1, gy = y0 + hy - 1, gx = hx - 1;
        bool inb = ((unsigned)gz < 32u) & ((unsigned)gy < 32u) &
                   ((unsigned)gx < 32u);
        int off = inb ? ((gz * 32 + gy) * 32 + gx) : 0;    // clamped: safe
        const float* xb = x + (size_t)(b * 64 + h * 32 + ch * 8) * 32768 + off;
        s16x8 v;
        #pragma unroll
        for (int j = 0; j < 8; ++j) {
          float f = xb[(size_t)j * 32768];
          v[j] = inb ? (short)f2bf(f) : (short)0;
        }
        *(s16x8*)&halo[task * 16] = v;
      }
    }
  };

  // ---- B staging: one kd-group = 9 taps x 4 KB = 2304 chunks, 5 rounds ----
  auto stage_B = [&](int h, int kd, int buf) {
    #pragma unroll 1
    for (int r = 0; r < 5; ++r) {
      int ci = r * 512 + tid;
      if (ci < 2304) {
        int tl = ci >> 8, off = ci & 255;
        int src = WS_W_OFF + ((kd * 9 + tl) * 2 + h) * 4096 + off * 16;
        __builtin_amdgcn_global_load_lds(
            (const GLOBAL_AS void*)(ws + src),
            (LDS_AS void*)(&blds[buf][ci * 16]),
            16, 0, 0);
      }
    }
  };

  f32x4 zero4 = {0.f, 0.f, 0.f, 0.f};
  f32x4 acc[4][4];
  #pragma unroll
  for (int mf = 0; mf < 4; ++mf)
    #pragma unroll
    for (int nf = 0; nf < 4; ++nf) acc[mf][nf] = zero4;

  // ---- 9 taps of one kd-slice, all operands from LDS, zero barriers ----
  auto run9 = [&](int kd, int buf) {
    #pragma unroll
    for (int tl = 0; tl < 9; ++tl) {
      const int kh = tl / 3, kw = tl % 3;        // compile-time
      s16x8 Bf[4], Af[4];
      #pragma unroll
      for (int nf = 0; nf < 4; ++nf)
        Bf[nf] = *(const s16x8*)&blds[buf][(tl * 256 + nf * 64 + lane) * 16];
      #pragma unroll
      for (int mf = 0; mf < 4; ++mf) {
        int p = ((zo + kd) * 6 + yo2 + (mf >> 1) + kh) * 34
              + kw + (mf & 1) * 16 + r15;
        Af[mf] = *(const s16x8*)&halo[p * 64 + hi4 * 16];
      }
      __builtin_amdgcn_s_setprio(1);
      #pragma unroll
      for (int mf = 0; mf < 4; ++mf)
        #pragma unroll
        for (int nf = 0; nf < 4; ++nf)
          acc[mf][nf] = __builtin_amdgcn_mfma_f32_16x16x32_bf16(
              Af[mf], Bf[nf], acc[mf][nf], 0, 0, 0);
      __builtin_amdgcn_s_setprio(0);
    }
  };

  // ---- half 0 ----
  stage_B(0, 0, 0); stage_halo(0);
  __syncthreads();                   // halo0 writes + B(kd0) loads drained
  stage_B(0, 1, 1);
  run9(0, 0);
  __syncthreads();                   // B(kd1) landed (free drain)
  stage_B(0, 2, 0);                  // buf0 free: kd0 reads done pre-barrier
  run9(1, 1);
  __syncthreads();                   // B(kd2) landed
  run9(2, 0);
  __syncthreads();                   // all halo0/blds reads done

  // ---- half 1 ----
  stage_B(1, 0, 1); stage_halo(1);
  __syncthreads();
  stage_B(1, 1, 0);
  run9(0, 1);
  __syncthreads();
  stage_B(1, 2, 1);
  run9(1, 0);
  __syncthreads();
  run9(2, 1);

  // ---- epilogue (verified 16x16 C/D): full-line coalesced stores ----
  const int z = z0 + zo;
  #pragma unroll
  for (int nf = 0; nf < 4; ++nf) {
    int cout = nf * 16 + r15;
    float bv = bias[cout];
    #pragma unroll
    for (int mf = 0; mf < 4; ++mf) {
      int y  = y0 + yo2 + (mf >> 1);
      int x0 = (mf & 1) * 16 + 4 * hi4;
      float* orow = out + ((size_t)((b * 64 + cout) * 32 + z) * 32 + y) * 32;
      f32x4 v;
      #pragma unroll
      for (int r = 0; r < 4; ++r) v[r] = acc[mf][nf][r] + bv;
      *(f32x4*)&orow[x0] = v;
    }
  }
}

extern "C" void kernel_launch(void* const* d_in, const int* in_sizes, int n_in,
                              void* d_out, int out_size, void* d_ws, size_t ws_size,
                              hipStream_t stream) {
  const float* x    = (const float*)d_in[0];
  const float* wgt  = (const float*)d_in[1];
  const float* bias = (const float*)d_in[2];
  float* out = (float*)d_out;
  char* ws = (char*)d_ws;

  wprep_kernel<<<432, 256, 0, stream>>>(wgt, (unsigned short*)(ws + WS_W_OFF));
  conv_kernel<<<256, 512, 0, stream>>>(x, bias, out, ws);
}

// Round 16
// 45.047 us; speedup vs baseline: 1.7699x; 1.7699x over previous
//
#include <hip/hip_runtime.h>
#include <hip/hip_bf16.h>

// ws layout (requires ws_size >= 17039360 B):
//   [0, 221184)        : weights as bf16 in 16x16x32 MFMA B-fragment order
//   [221184, 221440)   : 256 B of zeros (OOB halo source)
//   [262144, 17039360) : x_t = x transposed to [b][s][c] bf16 (16 MiB)
#define WS_W_OFF    0
#define WS_ZERO_OFF 221184
#define WS_XT_OFF   262144

typedef __attribute__((ext_vector_type(8))) short s16x8;
typedef __attribute__((ext_vector_type(4))) float f32x4;

#define GLOBAL_AS __attribute__((address_space(1)))
#define LDS_AS    __attribute__((address_space(3)))

__device__ __forceinline__ unsigned short f2bf(float f) {
  unsigned u = __builtin_bit_cast(unsigned, f);
  u = u + 0x7fffu + ((u >> 16) & 1u);
  return (unsigned short)(u >> 16);
}

// ---------------------------------------------------------------------------
// Fused prep. Blocks [0,432): weight repack (VERIFIED mapping, rounds 5..13).
// Blocks [432,944): x transpose via LDS tile for FULL-LINE stores.
//   Tile = 256 s x 64 c bf16 staged in LDS (rows padded to 144 B: both the
//   phase-1 ds_write_b128 (stride 144) and phase-2 ds_read_b128 spread
//   8 dwords/bank = floor). Phase-1 reads are 256x4B coalesced per cin;
//   phase-2 stores are 8 rows x 128 B = 1 KB contiguous per wave instr
//   (the old path wrote 16 B/lane at 128 B stride = partial sectors).
__global__ void prep_kernel(const float* __restrict__ x,
                            const float* __restrict__ w,
                            unsigned short* __restrict__ wsw,
                            float* __restrict__ zeros,
                            unsigned short* __restrict__ xt) {
  int blk = blockIdx.x;
  int tid = threadIdx.x;
  if (blk < 432) {
    int t = blk * 256 + tid;                     // 110592 threads exactly
    int tap  = t % 27;
    int cin  = (t / 27) & 63;
    int cout = t / (27 * 64);
    int h   = cin >> 5;
    int q   = (cin >> 3) & 3;
    int j   = cin & 7;
    int nf  = cout >> 4;
    int lane = q * 16 + (cout & 15);
    int dst = (((tap * 2 + h) * 4 + nf) * 64 + lane) * 8 + j;
    wsw[dst] = f2bf(w[t]);
    if (t < 64) zeros[t] = 0.0f;
  } else {
    __shared__ __align__(16) unsigned char tile[256 * 144];  // 36864 B
    int bi = blk - 432;                          // 512 tiles
    int b  = bi >> 7;
    int s0 = (bi & 127) * 256;
    const float* xb = x + (size_t)b * 64 * 32768 + s0 + tid;
    // phase 1: 8 cin-chunks; reads coalesced along s, LDS write conflict-free
    #pragma unroll
    for (int c0 = 0; c0 < 64; c0 += 8) {
      s16x8 v;
      #pragma unroll
      for (int j = 0; j < 8; ++j)
        v[j] = (short)f2bf(xb[(size_t)(c0 + j) * 32768]);
      *(s16x8*)&tile[tid * 144 + c0 * 2] = v;
    }
    __syncthreads();
    // phase 2: full-line stores, 1 KB contiguous per wave instruction
    #pragma unroll
    for (int it = 0; it < 8; ++it) {
      int row   = it * 32 + (tid >> 3);
      int col16 = tid & 7;
      s16x8 v = *(const s16x8*)&tile[row * 144 + col16 * 16];
      *(s16x8*)(xt + ((size_t)(b * 32768 + s0 + row) * 64 + col16 * 8)) = v;
    }
  }
}

// ---------------------------------------------------------------------------
// Implicit-GEMM conv (VERIFIED round 9, byte-identical): round-5 geometry +
// T4 counted-vmcnt B pipeline.
// Block = (b, z-pair, y-quad): 2z x 4y x 32x = 256 outputs x 64 couts,
// 4 waves. Wave w: z = z0+(w>>1), y-rows {y0+2(w&1),+1}: M_w = 64.
// K = 64 as two cin-halves; halo per half: 4z x 6y x 34x pos x 64 B = 52 KB
// -> grid 512 = 2 blocks/CU (8 waves/CU).
// B: inline-asm global_load_dwordx4, 3-slot rotation, 2 taps ahead; per-tap
// s_waitcnt vmcnt(8/4/0) + sched_barrier(0x106). Halo LINEAR (pos p at
// halo[p*64], chunk c at +c*16; A-read = 8 dwords/bank = b128 floor).
__global__ __launch_bounds__(256, 2) void conv_kernel(const float* __restrict__ bias,
                                                      float* __restrict__ out,
                                                      const char* __restrict__ ws) {
  __shared__ __align__(16) unsigned char halo[52 * 1024];  // 832 pos (816 used)

  const int tid  = threadIdx.x;
  const int lane = tid & 63;
  const int w    = tid >> 6;                     // wave id 0..3
  const int logical = (blockIdx.x & 7) * 64 + (blockIdx.x >> 3);
  const int yt = logical & 7, zt = (logical >> 3) & 15, b = logical >> 7;
  const int z0 = zt * 2, y0 = yt * 4;
  const int zo  = w >> 1;
  const int yo2 = (w & 1) * 2;

  const int r15 = lane & 15;
  const int hi4 = lane >> 4;

  const int sl_sub   = lane >> 2;
  const int sl_chunk = lane & 3;

  auto stage_halo = [&](int h) {
    for (int g = w; g < 52; g += 4) {            // 13 granules per wave
      int pos = g * 16 + sl_sub;
      int hz = pos / 204; int rem = pos - hz * 204;        // 204 = 6*34
      int hy = rem / 34;  int hx = rem - hy * 34;
      int gz = z0 + hz - 1, gy = y0 + hy - 1, gx = hx - 1;
      bool inb = (pos < 816) & ((unsigned)gz < 32u) &
                 ((unsigned)gy < 32u) & ((unsigned)gx < 32u);
      int s = (gz * 32 + gy) * 32 + gx;
      int src = inb ? (WS_XT_OFF + (b * 32768 + s) * 128 + h * 64 + sl_chunk * 16)
                    : WS_ZERO_OFF;
      __builtin_amdgcn_global_load_lds(
          (const GLOBAL_AS void*)(ws + src),
          (LDS_AS void*)(&halo[g * 1024 + lane * 16]),
          16, 0, 0);
    }
  };

  const char* wsb_lane = ws + WS_W_OFF + lane * 16;

  f32x4 zero4 = {0.f, 0.f, 0.f, 0.f};
  f32x4 acc[4][4];
  #pragma unroll
  for (int mf = 0; mf < 4; ++mf)
    #pragma unroll
    for (int nf = 0; nf < 4; ++nf) acc[mf][nf] = zero4;

  s16x8 Bb[3][4];

  auto issueB = [&](int slot, int h, int tap) {
    const char* bt = wsb_lane + (tap * 2 + h) * 4096;
    asm volatile("global_load_dwordx4 %0, %1, off"             : "=v"(Bb[slot][0]) : "v"(bt));
    asm volatile("global_load_dwordx4 %0, %1, off offset:1024" : "=v"(Bb[slot][1]) : "v"(bt));
    asm volatile("global_load_dwordx4 %0, %1, off offset:2048" : "=v"(Bb[slot][2]) : "v"(bt));
    asm volatile("global_load_dwordx4 %0, %1, off offset:3072" : "=v"(Bb[slot][3]) : "v"(bt));
  };

  auto loadA = [&](s16x8* a, int tap) {
    int kd = tap / 9; int r9 = tap - kd * 9;
    int kh = r9 / 3;  int kw = r9 - kh * 3;      // folds under full unroll
    int base = ((zo + kd) * 6 + (yo2 + kh)) * 34 + kw + r15;
    #pragma unroll
    for (int mf = 0; mf < 4; ++mf) {
      int pos = base + (mf >> 1) * 34 + (mf & 1) * 16;
      a[mf] = *(const s16x8*)&halo[pos * 64 + hi4 * 16];
    }
  };

  auto compute = [&](const s16x8* a, const s16x8* B) {
    #pragma unroll
    for (int mf = 0; mf < 4; ++mf)
      #pragma unroll
      for (int nf = 0; nf < 4; ++nf)
        acc[mf][nf] = __builtin_amdgcn_mfma_f32_16x16x32_bf16(
            a[mf], B[nf], acc[mf][nf], 0, 0, 0);
  };

  auto run27 = [&](int h) {
    #pragma unroll
    for (int tap = 0; tap < 27; ++tap) {
      if (tap < 25) issueB((tap + 2) % 3, h, tap + 2);     // static slot
      if (tap < 25)        { asm volatile("s_waitcnt vmcnt(8)"); }
      else if (tap == 25)  { asm volatile("s_waitcnt vmcnt(4)"); }
      else                 { asm volatile("s_waitcnt vmcnt(0)"); }
      __builtin_amdgcn_sched_barrier(0x106);   // DS_READ|VALU|SALU may cross
      s16x8 Af[4];
      loadA(Af, tap);
      compute(Af, Bb[tap % 3]);
    }
  };

  stage_halo(0);
  issueB(0, 0, 0); issueB(1, 0, 1);  // overlaps halo staging latency
  __syncthreads();                   // drains vmcnt; halo 0 + B(0,1) ready
  run27(0);

  issueB(0, 1, 0); issueB(1, 1, 1);  // half-1 B prologue (doesn't touch halo)
  __syncthreads();                   // all waves done reading half-0 halo
  stage_halo(1);
  __syncthreads();                   // halo 1 ready (drains everything)
  run27(1);

  const int z = z0 + zo;
  #pragma unroll
  for (int nf = 0; nf < 4; ++nf) {
    int cout = nf * 16 + r15;
    float bv = bias[cout];
    #pragma unroll
    for (int mf = 0; mf < 4; ++mf) {
      int y  = y0 + yo2 + (mf >> 1);
      int x0 = (mf & 1) * 16 + 4 * hi4;
      float* orow = out + ((size_t)((b * 64 + cout) * 32 + z) * 32 + y) * 32;
      f32x4 v;
      #pragma unroll
      for (int r = 0; r < 4; ++r) v[r] = acc[mf][nf][r] + bv;
      *(f32x4*)&orow[x0] = v;
    }
  }
}

extern "C" void kernel_launch(void* const* d_in, const int* in_sizes, int n_in,
                              void* d_out, int out_size, void* d_ws, size_t ws_size,
                              hipStream_t stream) {
  const float* x    = (const float*)d_in[0];
  const float* wgt  = (const float*)d_in[1];
  const float* bias = (const float*)d_in[2];
  float* out = (float*)d_out;
  char* ws = (char*)d_ws;

  prep_kernel<<<944, 256, 0, stream>>>(x, wgt,
                                       (unsigned short*)(ws + WS_W_OFF),
                                       (float*)(ws + WS_ZERO_OFF),
                                       (unsigned short*)(ws + WS_XT_OFF));
  conv_kernel<<<512, 256, 0, stream>>>(bias, out, ws);
}